// Round 4
// baseline (174.896 us; speedup 1.0000x reference)
//
#include <hip/hip_runtime.h>
#include <hip/hip_bf16.h>

#define B_ 4
#define T_ 256
#define S_ 256
#define D_ 512
#define TB 2   // t's per attention block

typedef __bf16 bf16x8 __attribute__((ext_vector_type(8)));
typedef float  floatx4 __attribute__((ext_vector_type(4)));

#define C2F 2.885390081777926f  // 2*log2(e)

static __device__ __forceinline__ unsigned short f2bf(float x) {
    __hip_bfloat16 h = __float2bfloat16(x);
    return *reinterpret_cast<unsigned short*>(&h);
}

// ---------------------------------------------------------------------------
// prep: z=3 -> fp32->bf16 convert of output & context (linear, float4).
//       z=0,1,2 -> transpose+convert Wq, Wc, Wout into n-major bf16 (WT[n][k])
//       so MFMA B-fragments are contiguous 16B loads. 32x32 LDS tiles.
// ---------------------------------------------------------------------------
__global__ __launch_bounds__(256) void prep(
    const float* __restrict__ output, const float* __restrict__ context,
    const float* __restrict__ Wq, const float* __restrict__ Wc,
    const float* __restrict__ Wout,
    unsigned short* __restrict__ out_b, unsigned short* __restrict__ ctx_b,
    unsigned short* __restrict__ WqT, unsigned short* __restrict__ WcT,
    unsigned short* __restrict__ WoutT)
{
    const int tid = threadIdx.x;
    const int z = blockIdx.z;

    if (z == 3) {
        size_t i = ((size_t)(blockIdx.y * gridDim.x + blockIdx.x) * 256 + tid) * 4;
        #pragma unroll
        for (int rep = 0; rep < 2; ++rep) {
            const float* src = rep ? context : output;
            unsigned short* dst = rep ? ctx_b : out_b;
            float4 v = *(const float4*)(src + i);
            ushort4 p;
            p.x = f2bf(v.x); p.y = f2bf(v.y); p.z = f2bf(v.z); p.w = f2bf(v.w);
            *(ushort4*)(dst + i) = p;
        }
        return;
    }

    const float* W; unsigned short* WT; int K;
    if      (z == 0) { W = Wq;   WT = WqT;   K = 512;  }
    else if (z == 1) { W = Wc;   WT = WcT;   K = 512;  }
    else             { W = Wout; WT = WoutT; K = 1024; }

    const int n0 = blockIdx.x * 32;
    const int k0 = blockIdx.y * 32;
    if (k0 >= K) return;

    __shared__ float tile[32][33];
    const int c = tid & 31, r = tid >> 5;
    #pragma unroll
    for (int i = 0; i < 4; ++i)
        tile[r + 8 * i][c] = W[(size_t)(k0 + r + 8 * i) * D_ + n0 + c];
    __syncthreads();
    #pragma unroll
    for (int i = 0; i < 4; ++i)
        WT[(size_t)(n0 + r + 8 * i) * K + k0 + c] = f2bf(tile[c][r + 8 * i]);
}

// ---------------------------------------------------------------------------
// Barrier-free MFMA bf16 GEMM, one 16x16 n-tile per wave (NT=1) for max wave
// count (latency-bound regime). N fixed at 512. A rows from A1 (k<KA) / A2
// (k>=KA), row stride KA. BT is n-major bf16 (BT[n][k], stride K).
// Epilogue modes: 0 = fp32 C[row*512+col] + bias
//                 1 = C2 * (acc + bias), normal layout      (wq')
//                 2 = C2 * acc, permuted [b][d>>2][s][d&3]  (uhp)
// ---------------------------------------------------------------------------
struct MArgs {
    const unsigned short* A1; const unsigned short* A2;
    const unsigned short* BT; const float* bias; float* C;
};

template<int K, int KA, int M0, int M1>
__global__ __launch_bounds__(256) void gemm_mfma(MArgs ga, MArgs gb)
{
    const int z = blockIdx.z;
    MArgs g = z ? gb : ga;
    const int mode = z ? M1 : M0;

    const int tid  = threadIdx.x;
    const int wave = tid >> 6, lane = tid & 63;
    const int l15  = lane & 15, quad = lane >> 4;
    const int mt   = blockIdx.y * 4 + wave;   // 16-row m-tile
    const int bn   = blockIdx.x * 16;
    const int am   = mt * 16 + l15;

    const unsigned short* A1p  = g.A1 + (size_t)am * KA + quad * 8;
    const unsigned short* A2p  = g.A2 + (size_t)am * KA + quad * 8;
    const unsigned short* Brow = g.BT + (size_t)(bn + l15) * K + quad * 8;

    floatx4 acc = (floatx4){0.f, 0.f, 0.f, 0.f};

    #pragma unroll 8
    for (int k0 = 0; k0 < K; k0 += 32) {
        const unsigned short* Ap = (k0 < KA) ? A1p + k0 : A2p + (k0 - KA);
        bf16x8 a = *(const bf16x8*)Ap;
        bf16x8 b = *(const bf16x8*)(Brow + k0);
        acc = __builtin_amdgcn_mfma_f32_16x16x32_bf16(a, b, acc, 0, 0, 0);
    }

    const int col = bn + l15;
    if (mode == 2) {
        #pragma unroll
        for (int r = 0; r < 4; ++r) {
            int row = mt * 16 + quad * 4 + r;
            int bb = row >> 8, ss = row & 255;
            g.C[(size_t)bb * S_ * D_ + (size_t)(col >> 2) * (S_ * 4)
                + ss * 4 + (col & 3)] = C2F * acc[r];
        }
    } else {
        float bv = g.bias ? g.bias[col] : 0.0f;
        #pragma unroll
        for (int r = 0; r < 4; ++r) {
            int row = mt * 16 + quad * 4 + r;
            float val = acc[r] + bv;
            if (mode == 1) val *= C2F;
            g.C[(size_t)row * 512 + col] = val;
        }
    }
}

// ---------------------------------------------------------------------------
// Fused score + masked softmax + mix. 512 threads; block = TB=2 t's of one b.
// Thread (s = tid&255, h = tid>>8) accumulates the d-half [256h, 256h+256).
// Inputs pre-scaled: wqs = C2*(output@Wq+bq), uhp = C2*(context@Wc) permuted
// to [b][d/4][s][4] -> float4 loads coalesced across the s-lanes.
// tanh(x) = 1 - 2/(exp2(C2*x)+1); score = Vsum - 2*sum_d v*r.
// ---------------------------------------------------------------------------
__global__ __launch_bounds__(512) void attn_fused(
    const float* __restrict__ wqs,      // (B,T,D), pre-scaled
    const float* __restrict__ uhp,      // (B,D/4,S,4), pre-scaled
    const float* __restrict__ context,  // (B,S,D) fp32
    const int*   __restrict__ mask,     // (B,S)
    const float* __restrict__ v,        // (D)
    float* __restrict__ attn_out,       // (B,T,S)
    unsigned short* __restrict__ mix_b) // (B,T,D) bf16
{
    const int bg  = blockIdx.x;
    const int b   = bg / (T_ / TB);
    const int t0  = (bg % (T_ / TB)) * TB;
    const int tid = threadIdx.x;
    const int s   = tid & 255;
    const int h   = tid >> 8;

    __shared__ float2 part[2][256];   // [h][s] = (acc_t0, acc_t1)
    __shared__ float2 red[256];
    __shared__ float  a_s[2][256];
    __shared__ float  vred[512];

    // Vsum = sum_d v[d]
    vred[tid] = v[tid];
    __syncthreads();
    for (int off = 256; off > 0; off >>= 1) {
        if (tid < off) vred[tid] += vred[tid + off];
        __syncthreads();
    }
    const float Vsum = vred[0];

    const float4* u4  = (const float4*)(uhp + (size_t)b * S_ * D_)
                        + (size_t)h * 64 * 256 + s;
    const float4* w0q = (const float4*)(wqs + (size_t)(b * T_ + t0) * D_) + h * 64;
    const float4* w1q = w0q + (D_ / 4);
    const float4* v4  = (const float4*)v + h * 64;

    float acc0 = 0.0f, acc1 = 0.0f;
    #pragma unroll 8
    for (int dq = 0; dq < 64; ++dq) {
        float4 u  = u4[(size_t)dq * 256];   // coalesced across s-lanes
        float4 w0 = w0q[dq];                // uniform -> s_load
        float4 w1 = w1q[dq];
        float4 vv = v4[dq];
        #pragma unroll
        for (int j = 0; j < 4; ++j) {
            float uu = ((const float*)&u)[j];
            float x0 = ((const float*)&w0)[j] + uu;
            float x1 = ((const float*)&w1)[j] + uu;
            float r0 = __builtin_amdgcn_rcpf(__builtin_amdgcn_exp2f(x0) + 1.0f);
            float r1 = __builtin_amdgcn_rcpf(__builtin_amdgcn_exp2f(x1) + 1.0f);
            float vj = ((const float*)&vv)[j];
            acc0 = fmaf(vj, r0, acc0);
            acc1 = fmaf(vj, r1, acc1);
        }
    }
    part[h][s] = make_float2(acc0, acc1);
    __syncthreads();

    float sc0 = 0.f, sc1 = 0.f;
    if (tid < 256) {
        float2 pa = part[0][tid], pb = part[1][tid];
        sc0 = Vsum - 2.0f * (pa.x + pb.x);
        sc1 = Vsum - 2.0f * (pa.y + pb.y);
        red[tid] = make_float2(sc0, sc1);
    }
    __syncthreads();
    for (int off = 128; off > 0; off >>= 1) {
        if (tid < off) {
            red[tid].x = fmaxf(red[tid].x, red[tid + off].x);
            red[tid].y = fmaxf(red[tid].y, red[tid + off].y);
        }
        __syncthreads();
    }
    float2 mx = red[0];
    __syncthreads();

    float p0 = 0.f, p1 = 0.f;
    if (tid < 256) {
        float keep = 1.0f - (float)mask[b * S_ + tid];
        p0 = __expf(sc0 - mx.x) * keep;
        p1 = __expf(sc1 - mx.y) * keep;
        red[tid] = make_float2(p0, p1);
    }
    __syncthreads();
    for (int off = 128; off > 0; off >>= 1) {
        if (tid < off) {
            red[tid].x += red[tid + off].x;
            red[tid].y += red[tid + off].y;
        }
        __syncthreads();
    }
    float2 denom = red[0];
    __syncthreads();

    if (tid < 256) {
        float a0 = p0 * __builtin_amdgcn_rcpf(denom.x);
        float a1 = p1 * __builtin_amdgcn_rcpf(denom.y);
        attn_out[(size_t)(b * T_ + t0 + 0) * S_ + tid] = a0;
        attn_out[(size_t)(b * T_ + t0 + 1) * S_ + tid] = a1;
        a_s[0][tid] = a0;
        a_s[1][tid] = a1;
    }
    __syncthreads();

    // mix[b,t,d=tid] = sum_s a[s] * context[b,s,d]; 4B coalesced loads
    const float* ctx = context + (size_t)b * S_ * D_ + tid;
    float m0 = 0.f, m1 = 0.f;
    #pragma unroll 8
    for (int s2 = 0; s2 < 256; ++s2) {
        float c = ctx[(size_t)s2 * D_];
        m0 = fmaf(a_s[0][s2], c, m0);
        m1 = fmaf(a_s[1][s2], c, m1);
    }
    mix_b[(size_t)(b * T_ + t0 + 0) * D_ + tid] = f2bf(m0);
    mix_b[(size_t)(b * T_ + t0 + 1) * D_ + tid] = f2bf(m1);
}

extern "C" void kernel_launch(void* const* d_in, const int* in_sizes, int n_in,
                              void* d_out, int out_size, void* d_ws, size_t ws_size,
                              hipStream_t stream) {
    const float* output  = (const float*)d_in[0];
    const float* context = (const float*)d_in[1];
    const int*   mask    = (const int*)d_in[2];
    const float* Wq      = (const float*)d_in[3];
    const float* bq      = (const float*)d_in[4];
    const float* Wc      = (const float*)d_in[5];
    const float* v       = (const float*)d_in[6];
    const float* Wout    = (const float*)d_in[7];
    const float* bout    = (const float*)d_in[8];

    float* out  = (float*)d_out;                       // (B,T,D)
    float* attn = out + (size_t)B_ * T_ * D_;          // (B,T,S)

    char* ws = (char*)d_ws;
    float* wqs = (float*)ws;                                      // 2 MB fp32
    float* uhp = (float*)(ws + (2u << 20));                       // 2 MB fp32
    unsigned short* out_b = (unsigned short*)(ws + (4u << 20));   // 1 MB bf16
    unsigned short* ctx_b = (unsigned short*)(ws + (5u << 20));   // 1 MB
    unsigned short* mix_b = (unsigned short*)(ws + (6u << 20));   // 1 MB
    unsigned short* WqT   = (unsigned short*)(ws + (7u << 20));   // 0.5 MB
    unsigned short* WcT   = (unsigned short*)(ws + (7u << 20) + (512u << 10));
    unsigned short* WoutT = (unsigned short*)(ws + (8u << 20));   // 1 MB

    dim3 blk(256);

    // convert + transpose to bf16
    prep<<<dim3(16, 32, 4), blk, 0, stream>>>(
        output, context, Wq, Wc, Wout, out_b, ctx_b, WqT, WcT, WoutT);

    // wqs = C2*(output@Wq + bq) [mode 1]  AND  uhp = C2*(context@Wc) permuted
    // [mode 2], one dispatch; 4096 waves total (16/CU)
    MArgs gq = { out_b, out_b, WqT, bq,      wqs };
    MArgs gc = { ctx_b, ctx_b, WcT, nullptr, uhp };
    gemm_mfma<512, 512, 1, 2><<<dim3(32, 16, 2), blk, 0, stream>>>(gq, gc);

    // fused score + softmax + mix (mix -> bf16)
    attn_fused<<<dim3(B_ * T_ / TB), dim3(512), 0, stream>>>(
        wqs, uhp, context, mask, v, attn, mix_b);

    // out = [mix, output] @ Wout + bout [mode 0]; 2048 waves (8/CU)
    MArgs go = { mix_b, out_b, WoutT, bout, out };
    gemm_mfma<1024, 512, 0, 0><<<dim3(32, 16, 1), blk, 0, stream>>>(go, go);
}

// Round 5
// 146.065 us; speedup vs baseline: 1.1974x; 1.1974x over previous
//
#include <hip/hip_runtime.h>
#include <hip/hip_bf16.h>

#define B_ 4
#define T_ 256
#define S_ 256
#define D_ 512
#define TB 4   // t's per attention block

typedef __bf16 bf16x8 __attribute__((ext_vector_type(8)));
typedef float  floatx4 __attribute__((ext_vector_type(4)));

#define C2F 2.885390081777926f  // 2*log2(e)

static __device__ __forceinline__ unsigned short f2bf(float x) {
    __hip_bfloat16 h = __float2bfloat16(x);
    return *reinterpret_cast<unsigned short*>(&h);
}
static __device__ __forceinline__ float asf(unsigned int u) {
    float f; __builtin_memcpy(&f, &u, 4); return f;
}

// ---------------------------------------------------------------------------
// prep: z=3 -> fp32->bf16 convert of output & context (linear, float4).
//       z=0,1,2 -> transpose+convert Wq, Wc, Wout into n-major bf16 (WT[n][k]).
// ---------------------------------------------------------------------------
__global__ __launch_bounds__(256) void prep(
    const float* __restrict__ output, const float* __restrict__ context,
    const float* __restrict__ Wq, const float* __restrict__ Wc,
    const float* __restrict__ Wout,
    unsigned short* __restrict__ out_b, unsigned short* __restrict__ ctx_b,
    unsigned short* __restrict__ WqT, unsigned short* __restrict__ WcT,
    unsigned short* __restrict__ WoutT)
{
    const int tid = threadIdx.x;
    const int z = blockIdx.z;

    if (z == 3) {
        size_t i = ((size_t)(blockIdx.y * gridDim.x + blockIdx.x) * 256 + tid) * 4;
        #pragma unroll
        for (int rep = 0; rep < 2; ++rep) {
            const float* src = rep ? context : output;
            unsigned short* dst = rep ? ctx_b : out_b;
            float4 v = *(const float4*)(src + i);
            ushort4 p;
            p.x = f2bf(v.x); p.y = f2bf(v.y); p.z = f2bf(v.z); p.w = f2bf(v.w);
            *(ushort4*)(dst + i) = p;
        }
        return;
    }

    const float* W; unsigned short* WT; int K;
    if      (z == 0) { W = Wq;   WT = WqT;   K = 512;  }
    else if (z == 1) { W = Wc;   WT = WcT;   K = 512;  }
    else             { W = Wout; WT = WoutT; K = 1024; }

    const int n0 = blockIdx.x * 32;
    const int k0 = blockIdx.y * 32;
    if (k0 >= K) return;

    __shared__ float tile[32][33];
    const int c = tid & 31, r = tid >> 5;
    #pragma unroll
    for (int i = 0; i < 4; ++i)
        tile[r + 8 * i][c] = W[(size_t)(k0 + r + 8 * i) * D_ + n0 + c];
    __syncthreads();
    #pragma unroll
    for (int i = 0; i < 4; ++i)
        WT[(size_t)(n0 + r + 8 * i) * K + k0 + c] = f2bf(tile[c][r + 8 * i]);
}

// ---------------------------------------------------------------------------
// Barrier-free MFMA bf16 GEMM, one 16x16 n-tile per wave. N fixed 512.
// Epilogue modes: 0 = fp32 C[row*512+col] + bias
//                 1 = C2 * (acc + bias), fp32 normal layout        (wqs)
//                 3 = bf16 C2*acc, permuted [b][d>>3][s][d&7]      (uhb)
// ---------------------------------------------------------------------------
struct MArgs {
    const unsigned short* A1; const unsigned short* A2;
    const unsigned short* BT; const float* bias; void* C;
};

template<int K, int KA, int M0, int M1>
__global__ __launch_bounds__(256) void gemm_mfma(MArgs ga, MArgs gb)
{
    const int z = blockIdx.z;
    MArgs g = z ? gb : ga;
    const int mode = z ? M1 : M0;

    const int tid  = threadIdx.x;
    const int wave = tid >> 6, lane = tid & 63;
    const int l15  = lane & 15, quad = lane >> 4;
    const int mt   = blockIdx.y * 4 + wave;
    const int bn   = blockIdx.x * 16;
    const int am   = mt * 16 + l15;

    const unsigned short* A1p  = g.A1 + (size_t)am * KA + quad * 8;
    const unsigned short* A2p  = g.A2 + (size_t)am * KA + quad * 8;
    const unsigned short* Brow = g.BT + (size_t)(bn + l15) * K + quad * 8;

    floatx4 acc = (floatx4){0.f, 0.f, 0.f, 0.f};

    #pragma unroll 8
    for (int k0 = 0; k0 < K; k0 += 32) {
        const unsigned short* Ap = (k0 < KA) ? A1p + k0 : A2p + (k0 - KA);
        bf16x8 a = *(const bf16x8*)Ap;
        bf16x8 b = *(const bf16x8*)(Brow + k0);
        acc = __builtin_amdgcn_mfma_f32_16x16x32_bf16(a, b, acc, 0, 0, 0);
    }

    const int col = bn + l15;
    if (mode == 3) {
        unsigned short* Cb = (unsigned short*)g.C;
        #pragma unroll
        for (int r = 0; r < 4; ++r) {
            int row = mt * 16 + quad * 4 + r;
            int bb = row >> 8, ss = row & 255;
            Cb[((size_t)(bb * 64 + (col >> 3)) * 256 + ss) * 8 + (col & 7)]
                = f2bf(C2F * acc[r]);
        }
    } else {
        float* Cf = (float*)g.C;
        float bv = g.bias ? g.bias[col] : 0.0f;
        #pragma unroll
        for (int r = 0; r < 4; ++r) {
            int row = mt * 16 + quad * 4 + r;
            float val = acc[r] + bv;
            if (mode == 1) val *= C2F;
            Cf[(size_t)row * 512 + col] = val;
        }
    }
}

// ---------------------------------------------------------------------------
// Fused score + masked softmax + mix. 512 threads; block = TB=4 t's of one b.
// Thread (s = tid&255, h = tid>>8) accumulates d-half [256h, 256h+256).
// wqs = C2*(output@Wq+bq) fp32; uhb = bf16 C2*(context@Wc) in [b][d/8][s][8]
// -> 16B coalesced loads across s-lanes. wq rows + v staged in LDS
// (broadcast b128 reads; no per-thread global ops in the hot loop).
// tanh(x) = 1 - 2/(exp2(x')+1) with x' pre-scaled; score = Vsum - 2*sum v*r.
// ---------------------------------------------------------------------------
__global__ __launch_bounds__(512) void attn_fused(
    const float* __restrict__ wqs,            // (B,T,D) pre-scaled fp32
    const unsigned short* __restrict__ uhb,   // (B,D/8,S,8) pre-scaled bf16
    const unsigned short* __restrict__ ctx_b, // (B,S,D) bf16
    const int*   __restrict__ mask,           // (B,S)
    const float* __restrict__ v,              // (D)
    float* __restrict__ attn_out,             // (B,T,S)
    unsigned short* __restrict__ mix_b)       // (B,T,D) bf16
{
    const int bg  = blockIdx.x;
    const int b   = bg / (T_ / TB);
    const int t0  = (bg % (T_ / TB)) * TB;
    const int tid = threadIdx.x;
    const int s   = tid & 255;
    const int h   = tid >> 8;

    __shared__ float   w_s[TB][D_];     // 8 KB
    __shared__ float   v_s[D_];         // 2 KB
    __shared__ floatx4 part[2][256];    // 8 KB
    __shared__ floatx4 red[256];        // 4 KB
    __shared__ float   a_s[TB][256];    // 4 KB
    __shared__ float   mixp[2][TB][D_]; // 16 KB

    // stage wq rows (pre-scaled) + v; compute Vsum
    #pragma unroll
    for (int t = 0; t < TB; ++t)
        w_s[t][tid] = wqs[(size_t)(b * T_ + t0 + t) * D_ + tid];
    v_s[tid] = v[tid];
    __syncthreads();

    if (tid < 256) red[tid].x = v_s[tid] + v_s[tid + 256];
    __syncthreads();
    for (int off = 128; off > 0; off >>= 1) {
        if (tid < off) red[tid].x += red[tid + off].x;
        __syncthreads();
    }
    const float Vsum = red[0].x;
    __syncthreads();

    floatx4 acc = (floatx4){0.f, 0.f, 0.f, 0.f};  // acc[t]
    const int do0 = h * 32;
    const uint4* u4 = (const uint4*)(uhb + ((size_t)(b * 64 + do0) * 256 + s) * 8);

    #pragma unroll 2
    for (int dd = 0; dd < 32; ++dd) {
        uint4 uu = u4[(size_t)dd * 256];   // 16B, coalesced across s-lanes
        float uf[8];
        uf[0] = asf(uu.x << 16); uf[1] = asf(uu.x & 0xffff0000u);
        uf[2] = asf(uu.y << 16); uf[3] = asf(uu.y & 0xffff0000u);
        uf[4] = asf(uu.z << 16); uf[5] = asf(uu.z & 0xffff0000u);
        uf[6] = asf(uu.w << 16); uf[7] = asf(uu.w & 0xffff0000u);

        const int dbase = (do0 + dd) * 8;
        float4 va = *(const float4*)&v_s[dbase];
        float4 vb = *(const float4*)&v_s[dbase + 4];
        #pragma unroll
        for (int t = 0; t < TB; ++t) {
            float4 wa = *(const float4*)&w_s[t][dbase];
            float4 wb = *(const float4*)&w_s[t][dbase + 4];
            float a0 = 0.f;
            #pragma unroll
            for (int j = 0; j < 4; ++j) {
                float x = ((const float*)&wa)[j] + uf[j];
                float r = __builtin_amdgcn_rcpf(__builtin_amdgcn_exp2f(x) + 1.0f);
                a0 = fmaf(((const float*)&va)[j], r, a0);
                float x2 = ((const float*)&wb)[j] + uf[4 + j];
                float r2 = __builtin_amdgcn_rcpf(__builtin_amdgcn_exp2f(x2) + 1.0f);
                a0 = fmaf(((const float*)&vb)[j], r2, a0);
            }
            acc[t] += a0;
        }
    }
    part[h][s] = acc;
    __syncthreads();

    floatx4 sc;
    if (tid < 256) {
        floatx4 pa = part[0][tid], pb = part[1][tid];
        #pragma unroll
        for (int t = 0; t < TB; ++t) sc[t] = Vsum - 2.0f * (pa[t] + pb[t]);
        red[tid] = sc;
    }
    __syncthreads();
    for (int off = 128; off > 0; off >>= 1) {
        if (tid < off) {
            #pragma unroll
            for (int t = 0; t < TB; ++t)
                red[tid][t] = fmaxf(red[tid][t], red[tid + off][t]);
        }
        __syncthreads();
    }
    floatx4 mx = red[0];
    __syncthreads();

    floatx4 p;
    if (tid < 256) {
        float keep = 1.0f - (float)mask[b * S_ + tid];
        #pragma unroll
        for (int t = 0; t < TB; ++t) p[t] = __expf(sc[t] - mx[t]) * keep;
        red[tid] = p;
    }
    __syncthreads();
    for (int off = 128; off > 0; off >>= 1) {
        if (tid < off) {
            #pragma unroll
            for (int t = 0; t < TB; ++t) red[tid][t] += red[tid + off][t];
        }
        __syncthreads();
    }
    floatx4 denom = red[0];
    __syncthreads();

    if (tid < 256) {
        #pragma unroll
        for (int t = 0; t < TB; ++t) {
            float a = p[t] * __builtin_amdgcn_rcpf(denom[t]);
            attn_out[(size_t)(b * T_ + t0 + t) * S_ + tid] = a;
            a_s[t][tid] = a;
        }
    }
    __syncthreads();

    // mix: thread (d2 = tid&255 -> d = 2*d2, 2*d2+1) over s-half [128h, +128)
    const int d2 = tid & 255;
    const int sh = h * 128;
    const unsigned short* cb = ctx_b + ((size_t)(b * S_) + sh) * D_ + 2 * d2;
    float m[TB][2] = {};
    #pragma unroll 8
    for (int s2 = 0; s2 < 128; ++s2) {
        unsigned int cc = *(const unsigned int*)(cb + (size_t)s2 * D_);
        float c0 = asf(cc << 16), c1 = asf(cc & 0xffff0000u);
        #pragma unroll
        for (int t = 0; t < TB; ++t) {
            float a = a_s[t][sh + s2];
            m[t][0] = fmaf(a, c0, m[t][0]);
            m[t][1] = fmaf(a, c1, m[t][1]);
        }
    }
    #pragma unroll
    for (int t = 0; t < TB; ++t) {
        mixp[h][t][2 * d2]     = m[t][0];
        mixp[h][t][2 * d2 + 1] = m[t][1];
    }
    __syncthreads();
    #pragma unroll
    for (int t = 0; t < TB; ++t) {
        float val = mixp[0][t][tid] + mixp[1][t][tid];
        mix_b[(size_t)(b * T_ + t0 + t) * D_ + tid] = f2bf(val);
    }
}

extern "C" void kernel_launch(void* const* d_in, const int* in_sizes, int n_in,
                              void* d_out, int out_size, void* d_ws, size_t ws_size,
                              hipStream_t stream) {
    const float* output  = (const float*)d_in[0];
    const float* context = (const float*)d_in[1];
    const int*   mask    = (const int*)d_in[2];
    const float* Wq      = (const float*)d_in[3];
    const float* bq      = (const float*)d_in[4];
    const float* Wc      = (const float*)d_in[5];
    const float* v       = (const float*)d_in[6];
    const float* Wout    = (const float*)d_in[7];
    const float* bout    = (const float*)d_in[8];

    float* out  = (float*)d_out;                       // (B,T,D)
    float* attn = out + (size_t)B_ * T_ * D_;          // (B,T,S)

    char* ws = (char*)d_ws;
    float* wqs = (float*)ws;                                      // 2 MB fp32
    unsigned short* uhb   = (unsigned short*)(ws + (2u << 20));   // 1 MB bf16
    unsigned short* out_b = (unsigned short*)(ws + (3u << 20));   // 1 MB
    unsigned short* ctx_b = (unsigned short*)(ws + (4u << 20));   // 1 MB
    unsigned short* mix_b = (unsigned short*)(ws + (5u << 20));   // 1 MB
    unsigned short* WqT   = (unsigned short*)(ws + (6u << 20));   // 0.5 MB
    unsigned short* WcT   = (unsigned short*)(ws + (6u << 20) + (512u << 10));
    unsigned short* WoutT = (unsigned short*)(ws + (7u << 20));   // 1 MB

    dim3 blk(256);

    prep<<<dim3(16, 32, 4), blk, 0, stream>>>(
        output, context, Wq, Wc, Wout, out_b, ctx_b, WqT, WcT, WoutT);

    // wqs = C2*(output@Wq + bq) [mode 1]  AND  uhb = bf16 C2*(context@Wc)
    // permuted [mode 3], one dispatch
    MArgs gq = { out_b, out_b, WqT, bq,      wqs };
    MArgs gc = { ctx_b, ctx_b, WcT, nullptr, uhb };
    gemm_mfma<512, 512, 1, 3><<<dim3(32, 16, 2), blk, 0, stream>>>(gq, gc);

    // fused score + softmax + mix (mix -> bf16)
    attn_fused<<<dim3(B_ * T_ / TB), dim3(512), 0, stream>>>(
        wqs, uhb, ctx_b, mask, v, attn, mix_b);

    // out = [mix, output] @ Wout + bout [mode 0]
    MArgs go = { mix_b, out_b, WoutT, bout, out };
    gemm_mfma<1024, 512, 0, 0><<<dim3(32, 16, 1), blk, 0, stream>>>(go, go);
}

// Round 6
// 134.640 us; speedup vs baseline: 1.2990x; 1.0849x over previous
//
#include <hip/hip_runtime.h>
#include <hip/hip_bf16.h>

#define B_ 4
#define T_ 256
#define S_ 256
#define D_ 512
#define TB 2   // t's per attention block

typedef __bf16 bf16x8 __attribute__((ext_vector_type(8)));
typedef float  floatx4 __attribute__((ext_vector_type(4)));

#define C2F 2.885390081777926f  // 2*log2(e)

static __device__ __forceinline__ unsigned short f2bf(float x) {
    __hip_bfloat16 h = __float2bfloat16(x);
    return *reinterpret_cast<unsigned short*>(&h);
}
static __device__ __forceinline__ float asf(unsigned int u) {
    float f; __builtin_memcpy(&f, &u, 4); return f;
}

// ---------------------------------------------------------------------------
// prep: z=3 -> fp32->bf16 convert of output & context (linear, float4).
//       z=0,1,2 -> transpose+convert Wq, Wc, Wout into n-major bf16 WT[n][k].
// ---------------------------------------------------------------------------
__global__ __launch_bounds__(256) void prep(
    const float* __restrict__ output, const float* __restrict__ context,
    const float* __restrict__ Wq, const float* __restrict__ Wc,
    const float* __restrict__ Wout,
    unsigned short* __restrict__ out_b, unsigned short* __restrict__ ctx_b,
    unsigned short* __restrict__ WqT, unsigned short* __restrict__ WcT,
    unsigned short* __restrict__ WoutT)
{
    const int tid = threadIdx.x;
    const int z = blockIdx.z;

    if (z == 3) {
        size_t i = ((size_t)(blockIdx.y * gridDim.x + blockIdx.x) * 256 + tid) * 4;
        #pragma unroll
        for (int rep = 0; rep < 2; ++rep) {
            const float* src = rep ? context : output;
            unsigned short* dst = rep ? ctx_b : out_b;
            float4 v = *(const float4*)(src + i);
            ushort4 p;
            p.x = f2bf(v.x); p.y = f2bf(v.y); p.z = f2bf(v.z); p.w = f2bf(v.w);
            *(ushort4*)(dst + i) = p;
        }
        return;
    }

    const float* W; unsigned short* WT; int K;
    if      (z == 0) { W = Wq;   WT = WqT;   K = 512;  }
    else if (z == 1) { W = Wc;   WT = WcT;   K = 512;  }
    else             { W = Wout; WT = WoutT; K = 1024; }

    const int n0 = blockIdx.x * 32;
    const int k0 = blockIdx.y * 32;
    if (k0 >= K) return;

    __shared__ float tile[32][33];
    const int c = tid & 31, r = tid >> 5;
    #pragma unroll
    for (int i = 0; i < 4; ++i)
        tile[r + 8 * i][c] = W[(size_t)(k0 + r + 8 * i) * D_ + n0 + c];
    __syncthreads();
    #pragma unroll
    for (int i = 0; i < 4; ++i)
        WT[(size_t)(n0 + r + 8 * i) * K + k0 + c] = f2bf(tile[c][r + 8 * i]);
}

// ---------------------------------------------------------------------------
// MFMA bf16 GEMM, 32x32 tile per wave (2x2 16x16 frags: 4 loads -> 4 MFMAs),
// 64x64 per block (4 waves). Barrier-free, fragments straight from L2.
// A: M x As row-major bf16. BT: n-major bf16, row stride Bs, k offset koff.
// Epilogue modes:
//   1: fp32 C2F*(acc + aux[col])        (wqs)
//   3: bf16 C2F*acc -> [b][d>>3][s][d&7] (uhb, rows are (b,s), col=d)
//   4: fp32 acc + aux[col]              (OB = output@Wout_bot + bout)
//   5: bf16 acc -> CWT[b][col][s]       (CW = context@Wout_top, transposed)
//   6: fp32 acc + aux[row*512+col]      (final: attn@CW + OB; B batched by b)
// ---------------------------------------------------------------------------
struct GArgs {
    const unsigned short* A;
    const unsigned short* BT;
    const float* aux;
    void* C;
    int As, Bs, koff, mode;
};

template<int K>
__global__ __launch_bounds__(256) void gemm2(GArgs g0, GArgs g1, GArgs g2, GArgs g3)
{
    const int z = blockIdx.z;
    GArgs g = (z == 0) ? g0 : (z == 1) ? g1 : (z == 2) ? g2 : g3;

    const int tid  = threadIdx.x;
    const int wave = tid >> 6, lane = tid & 63;
    const int l15  = lane & 15, quad = lane >> 4;
    const int m0 = blockIdx.y * 64 + (wave >> 1) * 32;
    const int n0 = blockIdx.x * 64 + (wave & 1) * 32;

    const unsigned short* Ap0 = g.A + (size_t)(m0 + l15) * g.As + quad * 8;
    const unsigned short* Ap1 = Ap0 + (size_t)16 * g.As;
    size_t boff = (g.mode == 6) ? (size_t)(blockIdx.y >> 2) * 512 * 256 : 0;
    const unsigned short* Bp0 = g.BT + boff + (size_t)(n0 + l15) * g.Bs
                                + g.koff + quad * 8;
    const unsigned short* Bp1 = Bp0 + (size_t)16 * g.Bs;

    floatx4 acc[2][2];
    #pragma unroll
    for (int i = 0; i < 2; ++i)
        #pragma unroll
        for (int j = 0; j < 2; ++j) acc[i][j] = (floatx4){0.f, 0.f, 0.f, 0.f};

    #pragma unroll 4
    for (int k = 0; k < K; k += 32) {
        bf16x8 a0 = *(const bf16x8*)(Ap0 + k);
        bf16x8 a1 = *(const bf16x8*)(Ap1 + k);
        bf16x8 b0 = *(const bf16x8*)(Bp0 + k);
        bf16x8 b1 = *(const bf16x8*)(Bp1 + k);
        acc[0][0] = __builtin_amdgcn_mfma_f32_16x16x32_bf16(a0, b0, acc[0][0], 0, 0, 0);
        acc[0][1] = __builtin_amdgcn_mfma_f32_16x16x32_bf16(a0, b1, acc[0][1], 0, 0, 0);
        acc[1][0] = __builtin_amdgcn_mfma_f32_16x16x32_bf16(a1, b0, acc[1][0], 0, 0, 0);
        acc[1][1] = __builtin_amdgcn_mfma_f32_16x16x32_bf16(a1, b1, acc[1][1], 0, 0, 0);
    }

    #pragma unroll
    for (int mi = 0; mi < 2; ++mi) {
        #pragma unroll
        for (int ni = 0; ni < 2; ++ni) {
            const int col = n0 + ni * 16 + l15;
            const int rbase = m0 + mi * 16 + quad * 4;
            if (g.mode == 3) {
                unsigned short* Cb = (unsigned short*)g.C;
                #pragma unroll
                for (int r = 0; r < 4; ++r) {
                    int row = rbase + r, bb = row >> 8, ss = row & 255;
                    Cb[((size_t)(bb * 64 + (col >> 3)) * 256 + ss) * 8 + (col & 7)]
                        = f2bf(C2F * acc[mi][ni][r]);
                }
            } else if (g.mode == 5) {
                unsigned short* Cb = (unsigned short*)g.C;
                #pragma unroll
                for (int r = 0; r < 4; ++r) {
                    int row = rbase + r, bb = row >> 8, ss = row & 255;
                    Cb[((size_t)bb * 512 + col) * 256 + ss] = f2bf(acc[mi][ni][r]);
                }
            } else if (g.mode == 6) {
                float* Cf = (float*)g.C;
                #pragma unroll
                for (int r = 0; r < 4; ++r) {
                    int row = rbase + r;
                    Cf[(size_t)row * 512 + col]
                        = acc[mi][ni][r] + g.aux[(size_t)row * 512 + col];
                }
            } else {
                float* Cf = (float*)g.C;
                float bv = g.aux ? g.aux[col] : 0.0f;
                #pragma unroll
                for (int r = 0; r < 4; ++r) {
                    int row = rbase + r;
                    float val = acc[mi][ni][r] + bv;
                    if (g.mode == 1) val *= C2F;
                    Cf[(size_t)row * 512 + col] = val;
                }
            }
        }
    }
}

// ---------------------------------------------------------------------------
// Fused score + masked softmax (NO mix — mix folded into the final GEMM).
// 512 threads; block = TB=2 t's of one b; thread (s=tid&255, h=tid>>8) owns
// d-half [256h, 256h+256). wqs = C2*(output@Wq+bq) fp32 staged in LDS
// (broadcast reads); uhb = bf16 C2*(context@Wc) in [b][d/8][s][8] -> 16B
// coalesced loads. tanh(x)=1-2/(exp2(x')+1); score = Vsum - 2*sum v*r.
// Writes attn fp32 (required output) + attn bf16 (A of the final GEMM).
// ---------------------------------------------------------------------------
__global__ __launch_bounds__(512) void attn_fused(
    const float* __restrict__ wqs,            // (B,T,D) pre-scaled fp32
    const unsigned short* __restrict__ uhb,   // (B,D/8,S,8) pre-scaled bf16
    const int*   __restrict__ mask,           // (B,S)
    const float* __restrict__ v,              // (D)
    float* __restrict__ attn_out,             // (B,T,S) fp32
    unsigned short* __restrict__ attn_b)      // (B,T,S) bf16
{
    const int bg  = blockIdx.x;
    const int b   = bg / (T_ / TB);
    const int t0  = (bg % (T_ / TB)) * TB;
    const int tid = threadIdx.x;
    const int s   = tid & 255;
    const int h   = tid >> 8;

    __shared__ float  w_s[TB][D_];    // 4 KB
    __shared__ float  v_s[D_];        // 2 KB
    __shared__ float2 part[2][256];   // 4 KB
    __shared__ float2 red[256];       // 2 KB

    #pragma unroll
    for (int t = 0; t < TB; ++t)
        w_s[t][tid] = wqs[(size_t)(b * T_ + t0 + t) * D_ + tid];
    v_s[tid] = v[tid];
    __syncthreads();

    if (tid < 256) red[tid].x = v_s[tid] + v_s[tid + 256];
    __syncthreads();
    for (int off = 128; off > 0; off >>= 1) {
        if (tid < off) red[tid].x += red[tid + off].x;
        __syncthreads();
    }
    const float Vsum = red[0].x;
    __syncthreads();

    float acc0 = 0.f, acc1 = 0.f;
    const int do0 = h * 32;
    const uint4* u4 = (const uint4*)(uhb + ((size_t)(b * 64 + do0) * 256 + s) * 8);

    #pragma unroll 4
    for (int dd = 0; dd < 32; ++dd) {
        uint4 uu = u4[(size_t)dd * 256];   // 16B, coalesced across s-lanes
        float uf[8];
        uf[0] = asf(uu.x << 16); uf[1] = asf(uu.x & 0xffff0000u);
        uf[2] = asf(uu.y << 16); uf[3] = asf(uu.y & 0xffff0000u);
        uf[4] = asf(uu.z << 16); uf[5] = asf(uu.z & 0xffff0000u);
        uf[6] = asf(uu.w << 16); uf[7] = asf(uu.w & 0xffff0000u);

        const int dbase = (do0 + dd) * 8;
        #pragma unroll
        for (int j = 0; j < 8; ++j) {
            float vv = v_s[dbase + j];
            float x0 = w_s[0][dbase + j] + uf[j];
            float x1 = w_s[1][dbase + j] + uf[j];
            float r0 = __builtin_amdgcn_rcpf(__builtin_amdgcn_exp2f(x0) + 1.0f);
            float r1 = __builtin_amdgcn_rcpf(__builtin_amdgcn_exp2f(x1) + 1.0f);
            acc0 = fmaf(vv, r0, acc0);
            acc1 = fmaf(vv, r1, acc1);
        }
    }
    part[h][s] = make_float2(acc0, acc1);
    __syncthreads();

    float sc0 = 0.f, sc1 = 0.f;
    if (tid < 256) {
        float2 pa = part[0][tid], pb = part[1][tid];
        sc0 = Vsum - 2.0f * (pa.x + pb.x);
        sc1 = Vsum - 2.0f * (pa.y + pb.y);
        red[tid] = make_float2(sc0, sc1);
    }
    __syncthreads();
    for (int off = 128; off > 0; off >>= 1) {
        if (tid < off) {
            red[tid].x = fmaxf(red[tid].x, red[tid + off].x);
            red[tid].y = fmaxf(red[tid].y, red[tid + off].y);
        }
        __syncthreads();
    }
    float2 mx = red[0];
    __syncthreads();

    float p0 = 0.f, p1 = 0.f;
    if (tid < 256) {
        float keep = 1.0f - (float)mask[b * S_ + tid];
        p0 = __expf(sc0 - mx.x) * keep;
        p1 = __expf(sc1 - mx.y) * keep;
        red[tid] = make_float2(p0, p1);
    }
    __syncthreads();
    for (int off = 128; off > 0; off >>= 1) {
        if (tid < off) {
            red[tid].x += red[tid + off].x;
            red[tid].y += red[tid + off].y;
        }
        __syncthreads();
    }
    float2 denom = red[0];

    if (tid < 256) {
        float a0 = p0 * __builtin_amdgcn_rcpf(denom.x);
        float a1 = p1 * __builtin_amdgcn_rcpf(denom.y);
        size_t r0i = (size_t)(b * T_ + t0 + 0) * S_ + tid;
        size_t r1i = (size_t)(b * T_ + t0 + 1) * S_ + tid;
        attn_out[r0i] = a0;
        attn_out[r1i] = a1;
        attn_b[r0i] = f2bf(a0);
        attn_b[r1i] = f2bf(a1);
    }
}

extern "C" void kernel_launch(void* const* d_in, const int* in_sizes, int n_in,
                              void* d_out, int out_size, void* d_ws, size_t ws_size,
                              hipStream_t stream) {
    const float* output  = (const float*)d_in[0];
    const float* context = (const float*)d_in[1];
    const int*   mask    = (const int*)d_in[2];
    const float* Wq      = (const float*)d_in[3];
    const float* bq      = (const float*)d_in[4];
    const float* Wc      = (const float*)d_in[5];
    const float* v       = (const float*)d_in[6];
    const float* Wout    = (const float*)d_in[7];
    const float* bout    = (const float*)d_in[8];

    float* out  = (float*)d_out;                       // (B,T,D)
    float* attn = out + (size_t)B_ * T_ * D_;          // (B,T,S)

    char* ws = (char*)d_ws;
    float* wqs          = (float*)ws;                             // 2 MB fp32
    float* OB           = (float*)(ws + (2u << 20));              // 2 MB fp32
    unsigned short* uhb    = (unsigned short*)(ws + (4u << 20));  // 1 MB
    unsigned short* out_b  = (unsigned short*)(ws + (5u << 20));  // 1 MB
    unsigned short* ctx_b  = (unsigned short*)(ws + (6u << 20));  // 1 MB
    unsigned short* WqT    = (unsigned short*)(ws + (7u << 20));  // 0.5 MB
    unsigned short* WcT    = (unsigned short*)(ws + (7u << 20) + (512u << 10));
    unsigned short* WoutT  = (unsigned short*)(ws + (8u << 20));  // 1 MB
    unsigned short* CWT    = (unsigned short*)(ws + (9u << 20));  // 1 MB
    unsigned short* attn_b = (unsigned short*)(ws + (10u << 20)); // 0.5 MB

    dim3 blk(256);

    prep<<<dim3(16, 32, 4), blk, 0, stream>>>(
        output, context, Wq, Wc, Wout, out_b, ctx_b, WqT, WcT, WoutT);

    // Pre-GEMMs, one dispatch (z-slices), all independent:
    //   z0: wqs = C2*(output@Wq + bq)           [mode 1]
    //   z1: uhb = bf16 C2*(context@Wc) permuted [mode 3]
    //   z2: OB  = output@Wout_bot + bout        [mode 4]
    //   z3: CWT = (context@Wout_top)^T bf16     [mode 5]
    GArgs gwq = { out_b, WqT,   bq,      wqs, 512, 512,   0, 1 };
    GArgs guh = { ctx_b, WcT,   nullptr, uhb, 512, 512,   0, 3 };
    GArgs gob = { out_b, WoutT, bout,    OB,  512, 1024, 512, 4 };
    GArgs gcw = { ctx_b, WoutT, nullptr, CWT, 512, 1024,   0, 5 };
    gemm2<512><<<dim3(8, 16, 4), blk, 0, stream>>>(gwq, guh, gob, gcw);

    // fused score + softmax (no mix)
    attn_fused<<<dim3(B_ * T_ / TB), dim3(512), 0, stream>>>(
        wqs, uhb, mask, v, attn, attn_b);

    // out = attn @ CW + OB   [mode 6, B batched per b]
    GArgs gf = { attn_b, CWT, OB, out, 256, 256, 0, 6 };
    gemm2<256><<<dim3(8, 16, 1), blk, 0, stream>>>(gf, gf, gf, gf);
}